// Round 9
// baseline (219.934 us; speedup 1.0000x reference)
//
#include <hip/hip_runtime.h>
#include <math.h>

#define BATCH 8
#define CH 64
#define NHEADS 8
#define NPIX 4096
#define QROWS 512

typedef __attribute__((ext_vector_type(8))) short short8v;
typedef __attribute__((ext_vector_type(16))) float f32x16;

// ---------------- reductions ----------------
__device__ inline float wave_sum(float v) {
#pragma unroll
    for (int off = 32; off; off >>= 1) v += __shfl_down(v, off, 64);
    return v;
}

// rne fp32 -> bf16 hi, and lo = bf16(f - hi)
__device__ inline void split_bf16(float f, short& h, short& l) {
    unsigned u = __float_as_uint(f);
    unsigned r = u + 0x7FFFu + ((u >> 16) & 1u);
    h = (short)(r >> 16);
    float hf = __uint_as_float(r & 0xFFFF0000u);
    float lf = f - hf;
    unsigned u2 = __float_as_uint(lf);
    unsigned r2 = u2 + 0x7FFFu + ((u2 >> 16) & 1u);
    l = (short)(r2 >> 16);
}

__device__ inline void split4(const float4 v, uint2& hi, uint2& lo) {
    short h0, h1, h2, h3, l0, l1, l2, l3;
    split_bf16(v.x, h0, l0); split_bf16(v.y, h1, l1);
    split_bf16(v.z, h2, l2); split_bf16(v.w, h3, l3);
    hi.x = (unsigned short)h0 | ((unsigned)(unsigned short)h1 << 16);
    hi.y = (unsigned short)h2 | ((unsigned)(unsigned short)h3 << 16);
    lo.x = (unsigned short)l0 | ((unsigned)(unsigned short)l1 << 16);
    lo.y = (unsigned short)l2 | ((unsigned)(unsigned short)l3 << 16);
}

// ---------------- 1) GroupNorm stats + zero (qsum+sraw+ksum contiguous) ----------------
// grid 520: blocks <256 do GN (b*32+g); blocks >=256 zero 270336 floats.
__global__ __launch_bounds__(256) void gn_zero_kernel(
    const float* __restrict__ x, const float* __restrict__ gamma,
    const float* __restrict__ beta, float* __restrict__ scale, float* __restrict__ shift,
    float* __restrict__ zbase) {
    if (blockIdx.x >= 256) {
        ((float4*)zbase)[(blockIdx.x - 256) * 256 + threadIdx.x] =
            make_float4(0.f, 0.f, 0.f, 0.f);
        return;
    }
    int b = blockIdx.x >> 5, g = blockIdx.x & 31;
    const float4* p = (const float4*)(x + ((size_t)b * CH + 2 * g) * NPIX);
    float s = 0.f, ss = 0.f;
#pragma unroll
    for (int i = 0; i < 8; ++i) {
        float4 v = p[threadIdx.x + i * 256];
        s += v.x + v.y + v.z + v.w;
        ss += v.x * v.x + v.y * v.y + v.z * v.z + v.w * v.w;
    }
    s = wave_sum(s);
    ss = wave_sum(ss);
    __shared__ float rs[4], rss[4];
    int lane = threadIdx.x & 63, wv = threadIdx.x >> 6;
    if (lane == 0) { rs[wv] = s; rss[wv] = ss; }
    __syncthreads();
    if (threadIdx.x == 0) {
        s = rs[0] + rs[1] + rs[2] + rs[3];
        ss = rss[0] + rss[1] + rss[2] + rss[3];
        float mu = s * (1.f / 8192.f);
        float var = ss * (1.f / 8192.f) - mu * mu;
        float rstd = rsqrtf(var + 1e-6f);
#pragma unroll
        for (int cc = 0; cc < 2; ++cc) {
            int c = 2 * g + cc;
            float sc = rstd * gamma[c];
            scale[b * CH + c] = sc;
            shift[b * CH + c] = beta[c] - mu * sc;
        }
    }
}

// ---------------- 2) GEMM1-Q: expq = exp(Wq@xn + bq); fused row sums (shfl+atomic) ----
// grid (32 pxtiles, 4 rowtiles, 8 b), 256 thr. qkv compact: [b][512][4096].
__global__ __launch_bounds__(256) void gemm1_q_kernel(
    const float* __restrict__ x, const float* __restrict__ scale_all,
    const float* __restrict__ shift_all,
    const float* __restrict__ Wq, const float* __restrict__ bq,
    float* __restrict__ qkv, float* __restrict__ qsum) {
    __shared__ __align__(16) char lds[65536];
    short* As = (short*)lds;
    short* Bs = (short*)(lds + 32768);
    float* Bf = (float*)lds;

    int t = threadIdx.x;
    int b = blockIdx.z;
    int row0 = blockIdx.y * 128, pix0 = blockIdx.x * 128;

    float4 w4[8];
#pragma unroll
    for (int i = 0; i < 8; ++i) {
        int idx = t + i * 256;
        int r = idx >> 4, c4 = idx & 15;
        w4[i] = *(const float4*)(Wq + (size_t)(row0 + r) * 64 + c4 * 4);
    }
    const float* scale = scale_all + b * CH;
    const float* shift = shift_all + b * CH;
#pragma unroll
    for (int i = 0; i < 8; ++i) {
        int idx = t + i * 256;
        int c = idx >> 5, p4 = (idx & 31) * 4;
        float4 v = *(const float4*)(x + ((size_t)b * CH + c) * NPIX + pix0 + p4);
        float sc = scale[c], sh = shift[c];
        v.x = fmaf(v.x, sc, sh); v.y = fmaf(v.y, sc, sh);
        v.z = fmaf(v.z, sc, sh); v.w = fmaf(v.w, sc, sh);
        *(float4*)&Bf[c * 132 + p4] = v;
    }
    __syncthreads();
    int mypx = t & 127, chalf = t >> 7;
    float xv[32];
#pragma unroll
    for (int e = 0; e < 32; ++e) xv[e] = Bf[(chalf * 32 + e) * 132 + mypx];
    __syncthreads();
#pragma unroll
    for (int i = 0; i < 8; ++i) {
        int idx = t + i * 256;
        int r = idx >> 4, c4 = (idx & 15) * 4;
        uint2 hi, lo;
        split4(w4[i], hi, lo);
        int chh = ((c4 >> 3) ^ (r & 7));
        int chl = ((8 + (c4 >> 3)) ^ (r & 7));
        *(uint2*)&As[r * 128 + chh * 8 + (c4 & 7)] = hi;
        *(uint2*)&As[r * 128 + chl * 8 + (c4 & 7)] = lo;
    }
    {
        short h[32], l[32];
#pragma unroll
        for (int e = 0; e < 32; ++e) split_bf16(xv[e], h[e], l[e]);
#pragma unroll
        for (int w = 0; w < 4; ++w) {
            short8v hv, lv;
#pragma unroll
            for (int e = 0; e < 8; ++e) { hv[e] = h[w * 8 + e]; lv[e] = l[w * 8 + e]; }
            int chh = ((chalf * 4 + w) ^ (mypx & 7));
            int chl = ((8 + chalf * 4 + w) ^ (mypx & 7));
            *(short8v*)&Bs[mypx * 128 + chh * 8] = hv;
            *(short8v*)&Bs[mypx * 128 + chl * 8] = lv;
        }
    }
    __syncthreads();

    int lane = t & 63, wid = t >> 6;
    int wm = wid >> 1, wn = wid & 1;
    int l31 = lane & 31, l7 = lane & 7, kg = lane >> 5;
    int arow = wm * 64 + l31;
    int brow = wn * 64 + l31;
    f32x16 acc[2][2];
#pragma unroll
    for (int mt = 0; mt < 2; ++mt)
#pragma unroll
        for (int nt = 0; nt < 2; ++nt)
#pragma unroll
            for (int e = 0; e < 16; ++e) acc[mt][nt][e] = 0.f;
    const int ACH[12] = {0, 2, 4, 6, 8, 10, 12, 14, 0, 2, 4, 6};
    const int BCH[12] = {0, 2, 4, 6, 0, 2, 4, 6, 8, 10, 12, 14};
#pragma unroll
    for (int ks = 0; ks < 12; ++ks) {
        int ach = ACH[ks] + kg, bch = BCH[ks] + kg;
        short8v a0 = *(const short8v*)&As[arow * 128 + ((ach ^ l7) << 3)];
        short8v a1 = *(const short8v*)&As[(arow + 32) * 128 + ((ach ^ l7) << 3)];
        short8v b0 = *(const short8v*)&Bs[brow * 128 + ((bch ^ l7) << 3)];
        short8v b1 = *(const short8v*)&Bs[(brow + 32) * 128 + ((bch ^ l7) << 3)];
        acc[0][0] = __builtin_amdgcn_mfma_f32_32x32x16_bf16(a0, b0, acc[0][0], 0, 0, 0);
        acc[0][1] = __builtin_amdgcn_mfma_f32_32x32x16_bf16(a0, b1, acc[0][1], 0, 0, 0);
        acc[1][0] = __builtin_amdgcn_mfma_f32_32x32x16_bf16(a1, b0, acc[1][0], 0, 0, 0);
        acc[1][1] = __builtin_amdgcn_mfma_f32_32x32x16_bf16(a1, b1, acc[1][1], 0, 0, 0);
    }
    // epilogue: exp, store, and per-row sum (row = fixed per (mt,j,kg); 32 lanes hold 2 px each)
#pragma unroll
    for (int mt = 0; mt < 2; ++mt) {
#pragma unroll
        for (int j = 0; j < 16; ++j) {
            int rl = wm * 64 + mt * 32 + (j & 3) + 8 * (j >> 2) + 4 * kg;
            float bi = bq[row0 + rl];
            float e0 = __expf(acc[mt][0][j] + bi);
            float e1 = __expf(acc[mt][1][j] + bi);
            float* o = qkv + ((size_t)b * QROWS + row0 + rl) * NPIX + pix0;
            o[wn * 64 + l31] = e0;
            o[wn * 64 + 32 + l31] = e1;
            float rsum = e0 + e1;
            rsum += __shfl_xor(rsum, 1);
            rsum += __shfl_xor(rsum, 2);
            rsum += __shfl_xor(rsum, 4);
            rsum += __shfl_xor(rsum, 8);
            rsum += __shfl_xor(rsum, 16);
            if (l31 == 0) atomicAdd(&qsum[b * 512 + row0 + rl], rsum);
        }
    }
}

// ---------------- 3) fused KV, 512 threads (8 waves = 2 waves/SIMD for latency hiding) ----
// grid (32 pxtiles, 4 kvtiles, 8 b). Projection swapped: A=xn(px), B=W(krow);
// wave (wm=wid>>2: px half, wn=wid&3: krow quarter) -> acc[2] (64px x 32krow).
// expk/v -> LDS chunk-XOR bufs; contraction wave (hh=wid>>2: head, pp,cc) computes
// one 32x32 s-tile over K=128 px, 3-term; atomicAdd -> sraw. k,v never hit HBM.
__global__ __launch_bounds__(512) void gemm_kv_fused_kernel(
    const float* __restrict__ x, const float* __restrict__ scale_all,
    const float* __restrict__ shift_all,
    const float* __restrict__ Wk, const float* __restrict__ bk,
    const float* __restrict__ Wv, const float* __restrict__ bv,
    float* __restrict__ sraw, float* __restrict__ ksum) {
    __shared__ __align__(16) char lds[131072];
    short* As = (short*)lds;
    short* Bs = (short*)(lds + 32768);
    short* Eh = (short*)(lds + 65536);
    short* El = (short*)(lds + 98304);
    short* Vh = (short*)lds;            // overlays As after v-projection
    short* Vl = (short*)(lds + 32768);  // overlays Bs
    float* Bf = (float*)lds;

    int t = threadIdx.x;
    int b = blockIdx.z;
    int r = blockIdx.y;                 // k rows [128r,128r+128) = heads 2r,2r+1
    int pix0 = blockIdx.x * 128;

    float4 w4[4];
#pragma unroll
    for (int i = 0; i < 4; ++i) {
        int idx = t + i * 512;
        int rr = idx >> 4, c4 = idx & 15;
        w4[i] = *(const float4*)(Wk + (size_t)(r * 128 + rr) * 64 + c4 * 4);
    }
    const float* scale = scale_all + b * CH;
    const float* shift = shift_all + b * CH;
#pragma unroll
    for (int i = 0; i < 4; ++i) {
        int idx = t + i * 512;
        int c = idx >> 5, p4 = (idx & 31) * 4;
        float4 v = *(const float4*)(x + ((size_t)b * CH + c) * NPIX + pix0 + p4);
        float sc = scale[c], sh = shift[c];
        v.x = fmaf(v.x, sc, sh); v.y = fmaf(v.y, sc, sh);
        v.z = fmaf(v.z, sc, sh); v.w = fmaf(v.w, sc, sh);
        *(float4*)&Bf[c * 132 + p4] = v;
    }
    __syncthreads();
    int mypx = t & 127, cq = t >> 7;    // cq 0..3: 16 channels each
    float xv[16];
#pragma unroll
    for (int e = 0; e < 16; ++e) xv[e] = Bf[(cq * 16 + e) * 132 + mypx];
    __syncthreads();
#pragma unroll
    for (int i = 0; i < 4; ++i) {
        int idx = t + i * 512;
        int rr = idx >> 4, c4 = (idx & 15) * 4;
        uint2 hi, lo;
        split4(w4[i], hi, lo);
        int chh = ((c4 >> 3) ^ (rr & 7));
        int chl = ((8 + (c4 >> 3)) ^ (rr & 7));
        *(uint2*)&As[rr * 128 + chh * 8 + (c4 & 7)] = hi;
        *(uint2*)&As[rr * 128 + chl * 8 + (c4 & 7)] = lo;
    }
    {
        short h[16], l[16];
#pragma unroll
        for (int e = 0; e < 16; ++e) split_bf16(xv[e], h[e], l[e]);
#pragma unroll
        for (int w = 0; w < 2; ++w) {
            short8v hv, lv;
#pragma unroll
            for (int e = 0; e < 8; ++e) { hv[e] = h[w * 8 + e]; lv[e] = l[w * 8 + e]; }
            int chh = ((cq * 2 + w) ^ (mypx & 7));
            int chl = ((8 + cq * 2 + w) ^ (mypx & 7));
            *(short8v*)&Bs[mypx * 128 + chh * 8] = hv;
            *(short8v*)&Bs[mypx * 128 + chl * 8] = lv;
        }
    }
    float4 w4v[4];
#pragma unroll
    for (int i = 0; i < 4; ++i) {
        int idx = t + i * 512;
        int rr = idx >> 4, c4 = idx & 15;
        w4v[i] = *(const float4*)(Wv + (size_t)(r * 128 + rr) * 64 + c4 * 4);
    }
    __syncthreads();

    int lane = t & 63, wid = t >> 6;    // wid 0..7
    int wm = wid >> 2, wn = wid & 3;    // px half, krow quarter
    int l31 = lane & 31, l7 = lane & 7, kg = lane >> 5;
    int axrow = wm * 64 + l31;
    int bwrow = wn * 32 + l31;
    const int XCH[12] = {0, 2, 4, 6, 8, 10, 12, 14, 0, 2, 4, 6};
    const int WCH[12] = {0, 2, 4, 6, 0, 2, 4, 6, 8, 10, 12, 14};

    f32x16 acc[2];
#pragma unroll
    for (int mt = 0; mt < 2; ++mt)
#pragma unroll
        for (int e = 0; e < 16; ++e) acc[mt][e] = 0.f;
#pragma unroll
    for (int ks = 0; ks < 12; ++ks) {
        int xch = XCH[ks] + kg, wch = WCH[ks] + kg;
        short8v a0 = *(const short8v*)&Bs[axrow * 128 + ((xch ^ l7) << 3)];
        short8v a1 = *(const short8v*)&Bs[(axrow + 32) * 128 + ((xch ^ l7) << 3)];
        short8v b0 = *(const short8v*)&As[bwrow * 128 + ((wch ^ l7) << 3)];
        acc[0] = __builtin_amdgcn_mfma_f32_32x32x16_bf16(a0, b0, acc[0], 0, 0, 0);
        acc[1] = __builtin_amdgcn_mfma_f32_32x32x16_bf16(a1, b0, acc[1], 0, 0, 0);
    }
    // epilogue k: exp, ksum partial, Eh/El writes
    {
        int krow = wn * 32 + l31;
        float bi = bk[r * 128 + krow];
        float part = 0.f;
#pragma unroll
        for (int mt = 0; mt < 2; ++mt) {
#pragma unroll
            for (int g = 0; g < 4; ++g) {
                float4 ev;
                ev.x = __expf(acc[mt][g * 4 + 0] + bi);
                ev.y = __expf(acc[mt][g * 4 + 1] + bi);
                ev.z = __expf(acc[mt][g * 4 + 2] + bi);
                ev.w = __expf(acc[mt][g * 4 + 3] + bi);
                part += ev.x + ev.y + ev.z + ev.w;
                uint2 hi, lo;
                split4(ev, hi, lo);
                int ch = wm * 8 + mt * 4 + g;
                int off = krow * 128 + ((ch ^ (krow & 7)) << 3) + 4 * kg;
                *(uint2*)&Eh[off] = hi;
                *(uint2*)&El[off] = lo;
            }
        }
        part += __shfl_xor(part, 32);
        if (kg == 0) atomicAdd(&ksum[b * 512 + r * 128 + krow], part);
    }
    __syncthreads();
    // restage Wv -> As
#pragma unroll
    for (int i = 0; i < 4; ++i) {
        int idx = t + i * 512;
        int rr = idx >> 4, c4 = (idx & 15) * 4;
        uint2 hi, lo;
        split4(w4v[i], hi, lo);
        int chh = ((c4 >> 3) ^ (rr & 7));
        int chl = ((8 + (c4 >> 3)) ^ (rr & 7));
        *(uint2*)&As[rr * 128 + chh * 8 + (c4 & 7)] = hi;
        *(uint2*)&As[rr * 128 + chl * 8 + (c4 & 7)] = lo;
    }
    __syncthreads();
    // v projection
#pragma unroll
    for (int mt = 0; mt < 2; ++mt)
#pragma unroll
        for (int e = 0; e < 16; ++e) acc[mt][e] = 0.f;
#pragma unroll
    for (int ks = 0; ks < 12; ++ks) {
        int xch = XCH[ks] + kg, wch = WCH[ks] + kg;
        short8v a0 = *(const short8v*)&Bs[axrow * 128 + ((xch ^ l7) << 3)];
        short8v a1 = *(const short8v*)&Bs[(axrow + 32) * 128 + ((xch ^ l7) << 3)];
        short8v b0 = *(const short8v*)&As[bwrow * 128 + ((wch ^ l7) << 3)];
        acc[0] = __builtin_amdgcn_mfma_f32_32x32x16_bf16(a0, b0, acc[0], 0, 0, 0);
        acc[1] = __builtin_amdgcn_mfma_f32_32x32x16_bf16(a1, b0, acc[1], 0, 0, 0);
    }
    __syncthreads();   // all As/Bs reads done -> V may overlay
    {
        int vrow = wn * 32 + l31;
        float bi = bv[r * 128 + vrow];
#pragma unroll
        for (int mt = 0; mt < 2; ++mt) {
#pragma unroll
            for (int g = 0; g < 4; ++g) {
                float4 vv;
                vv.x = acc[mt][g * 4 + 0] + bi;
                vv.y = acc[mt][g * 4 + 1] + bi;
                vv.z = acc[mt][g * 4 + 2] + bi;
                vv.w = acc[mt][g * 4 + 3] + bi;
                uint2 hi, lo;
                split4(vv, hi, lo);
                int ch = wm * 8 + mt * 4 + g;
                int off = vrow * 128 + ((ch ^ (vrow & 7)) << 3) + 4 * kg;
                *(uint2*)&Vh[off] = hi;
                *(uint2*)&Vl[off] = lo;
            }
        }
    }
    __syncthreads();
    // contraction: wave (hh=wid>>2, pp, cc) -> one 32x32 s-tile, K=128 px, 3 terms
    int hh = wid >> 2, pc = wid & 3;
    int pp = pc >> 1, cc = pc & 1;
    int ar = (hh * 64 + pp * 32 + l31) * 128;
    int br = (hh * 64 + cc * 32 + l31) * 128;
    f32x16 cacc;
#pragma unroll
    for (int e = 0; e < 16; ++e) cacc[e] = 0.f;
#pragma unroll
    for (int s = 0; s < 8; ++s) {
        int ch = (((2 * s + kg) ^ l7) << 3);
        short8v a = *(const short8v*)&Eh[ar + ch];
        short8v bb = *(const short8v*)&Vh[br + ch];
        cacc = __builtin_amdgcn_mfma_f32_32x32x16_bf16(a, bb, cacc, 0, 0, 0);
    }
#pragma unroll
    for (int s = 0; s < 8; ++s) {
        int ch = (((2 * s + kg) ^ l7) << 3);
        short8v a = *(const short8v*)&El[ar + ch];
        short8v bb = *(const short8v*)&Vh[br + ch];
        cacc = __builtin_amdgcn_mfma_f32_32x32x16_bf16(a, bb, cacc, 0, 0, 0);
    }
#pragma unroll
    for (int s = 0; s < 8; ++s) {
        int ch = (((2 * s + kg) ^ l7) << 3);
        short8v a = *(const short8v*)&Eh[ar + ch];
        short8v bb = *(const short8v*)&Vl[br + ch];
        cacc = __builtin_amdgcn_mfma_f32_32x32x16_bf16(a, bb, cacc, 0, 0, 0);
    }
    int h = r * 2 + hh;
    float* sr = sraw + (((size_t)b * 8 + h) * 64) * 64;
#pragma unroll
    for (int j = 0; j < 16; ++j) {
        int p = pp * 32 + (j & 3) + 8 * (j >> 2) + 4 * kg;
        int c = cc * 32 + l31;
        atomicAdd(&sr[p * 64 + c], cacc[j]);
    }
}

// ---------------- 4) T[b,o,hp] = (Wo[o,h*64:] . sraw[b,h,p,:]) / (8*ksum*qsum) --------
__global__ __launch_bounds__(256) void t_kernel(
    const float* __restrict__ sraw, const float* __restrict__ qsum_all,
    const float* __restrict__ ksum_all, const float* __restrict__ Wo, float* __restrict__ T) {
    int idx = blockIdx.x * 256 + threadIdx.x;
    int hp = idx & 511, o = (idx >> 9) & 63, b = idx >> 15;
    int h = hp >> 6, pp = hp & 63;
    const float* srow = sraw + (((size_t)b * 8 + h) * 64 + pp) * 64;
    const float* wrow = Wo + (size_t)o * 512 + h * 64;
    float acc = 0.f;
#pragma unroll
    for (int c = 0; c < 64; ++c) acc += wrow[c] * srow[c];
    float ks = ksum_all[b * 512 + hp];
    float qs = qsum_all[b * 512 + hp];
    T[idx] = acc / (8.f * ks * qs);
}

// ---------------- 5) GEMM2 via MFMA: out[b,o,px] = bo[o] + sum_hp T[o,hp]*expq[hp,px] --
__global__ __launch_bounds__(256) void gemm2_mfma_kernel(
    const float* __restrict__ qkv, const float* __restrict__ T_all,
    const float* __restrict__ bo, float* __restrict__ out) {
    __shared__ __align__(16) short lds[16384];
    short* As = lds;
    short* Bs = lds + 8192;
    int pix0 = blockIdx.x * 64, b = blockIdx.y;
    const float* Tb = T_all + (size_t)b * 64 * 512;
    const float* qb = qkv + (size_t)b * QROWS * NPIX;
    int t = threadIdx.x;
    int lane = t & 63, wid = t >> 6;
    int wm = wid & 1, wn = wid >> 1;
    int l31 = lane & 31, l7 = lane & 7, kg = lane >> 5;
    int arow = (wm * 32 + l31) * 128;
    int brow = (wn * 32 + l31) * 128;
    int px0 = t & 63, hpq = (t >> 6) * 16;
    f32x16 acc;
#pragma unroll
    for (int e = 0; e < 16; ++e) acc[e] = 0.f;
    for (int it = 0; it < 8; ++it) {
        __syncthreads();
#pragma unroll
        for (int i = 0; i < 4; ++i) {
            int e4 = t + i * 256;
            int o = e4 >> 4, p4 = (e4 & 15) * 4;
            int chx = (((p4 >> 3) ^ (o & 7)) << 3) + (p4 & 7);
            float4 tv = *(const float4*)(Tb + (size_t)o * 512 + it * 64 + p4);
            uint2 hi, lo;
            split4(tv, hi, lo);
            *(uint2*)&As[o * 128 + chx] = hi;
            *(uint2*)&As[o * 128 + 64 + chx] = lo;
        }
        float colv[16];
#pragma unroll
        for (int e = 0; e < 16; ++e)
            colv[e] = qb[(size_t)(it * 64 + hpq + e) * NPIX + pix0 + px0];
#pragma unroll
        for (int qd = 0; qd < 4; ++qd) {
            int hpl = hpq + qd * 4;
            float4 v4 = make_float4(colv[qd * 4], colv[qd * 4 + 1],
                                    colv[qd * 4 + 2], colv[qd * 4 + 3]);
            uint2 hi, lo;
            split4(v4, hi, lo);
            int chx = (((hpl >> 3) ^ (px0 & 7)) << 3) + (hpl & 7);
            *(uint2*)&Bs[px0 * 128 + chx] = hi;
            *(uint2*)&Bs[px0 * 128 + 64 + chx] = lo;
        }
        __syncthreads();
        short8v ah[4], al[4], bh[4], bl[4];
#pragma unroll
        for (int ks = 0; ks < 4; ++ks) {
            int ch = ((ks * 2 + kg) ^ l7) << 3;
            ah[ks] = *(const short8v*)&As[arow + ch];
            al[ks] = *(const short8v*)&As[arow + 64 + ch];
            bh[ks] = *(const short8v*)&Bs[brow + ch];
            bl[ks] = *(const short8v*)&Bs[brow + 64 + ch];
        }
#pragma unroll
        for (int ks = 0; ks < 4; ++ks) {
            acc = __builtin_amdgcn_mfma_f32_32x32x16_bf16(ah[ks], bh[ks], acc, 0, 0, 0);
            acc = __builtin_amdgcn_mfma_f32_32x32x16_bf16(al[ks], bh[ks], acc, 0, 0, 0);
            acc = __builtin_amdgcn_mfma_f32_32x32x16_bf16(ah[ks], bl[ks], acc, 0, 0, 0);
        }
    }
#pragma unroll
    for (int j = 0; j < 16; ++j) {
        int o = wm * 32 + (j & 3) + 8 * (j >> 2) + 4 * kg;
        out[((size_t)b * 64 + o) * NPIX + pix0 + wn * 32 + l31] = acc[j] + bo[o];
    }
}

// ---------------- workspace layout (floats) ----------------
#define OFF_SCALE 0                     // [8][64]          = 512
#define OFF_SHIFT 512                   // [8][64]          = 512
#define OFF_QSUM  1024                  // [8][512]         = 4096
#define OFF_SRAW  5120                  // [8][8][64][64]   = 262144
#define OFF_KSUM  267264                // [8][512]         = 4096
#define OFF_T     271360                // [8][64][512]     = 262144
#define OFF_QKV   533504                // [8][512][4096]   = 16777216 (expq only)
#define WS_FLOATS (533504 + 16777216)
// zero range [OFF_QSUM, OFF_KSUM+4096) = 270336 floats = 67584 float4 = 264 blocks * 256

extern "C" void kernel_launch(void* const* d_in, const int* in_sizes, int n_in,
                              void* d_out, int out_size, void* d_ws, size_t ws_size,
                              hipStream_t stream) {
    const float* x  = (const float*)d_in[0];
    const float* gg = (const float*)d_in[1];
    const float* gb = (const float*)d_in[2];
    const float* Wq = (const float*)d_in[3];
    const float* bq = (const float*)d_in[4];
    const float* Wk = (const float*)d_in[5];
    const float* bk = (const float*)d_in[6];
    const float* Wv = (const float*)d_in[7];
    const float* bv = (const float*)d_in[8];
    const float* Wo = (const float*)d_in[9];
    const float* bo = (const float*)d_in[10];
    float* out = (float*)d_out;
    float* ws = (float*)d_ws;
    if (ws_size < (size_t)WS_FLOATS * sizeof(float)) return;

    float* scale = ws + OFF_SCALE;
    float* shift = ws + OFF_SHIFT;
    float* qsum  = ws + OFF_QSUM;
    float* sraw  = ws + OFF_SRAW;
    float* ksum  = ws + OFF_KSUM;
    float* T     = ws + OFF_T;
    float* qkv   = ws + OFF_QKV;

    gn_zero_kernel<<<520, 256, 0, stream>>>(x, gg, gb, scale, shift, qsum);
    gemm1_q_kernel<<<dim3(32, 4, 8), 256, 0, stream>>>(x, scale, shift, Wq, bq, qkv, qsum);
    gemm_kv_fused_kernel<<<dim3(32, 4, 8), 512, 0, stream>>>(x, scale, shift, Wk, bk, Wv, bv,
                                                             sraw, ksum);
    t_kernel<<<1024, 256, 0, stream>>>(sraw, qsum, ksum, Wo, T);
    gemm2_mfma_kernel<<<dim3(64, 8), 256, 0, stream>>>(qkv, T, bo, out);
}

// Round 10
// 188.072 us; speedup vs baseline: 1.1694x; 1.1694x over previous
//
#include <hip/hip_runtime.h>
#include <math.h>

#define BATCH 8
#define CH 64
#define NHEADS 8
#define NPIX 4096
#define QROWS 512

typedef __attribute__((ext_vector_type(8))) short short8v;
typedef __attribute__((ext_vector_type(16))) float f32x16;

// ---------------- reductions ----------------
__device__ inline float wave_sum(float v) {
#pragma unroll
    for (int off = 32; off; off >>= 1) v += __shfl_down(v, off, 64);
    return v;
}

// rne fp32 -> bf16 hi, and lo = bf16(f - hi)
__device__ inline void split_bf16(float f, short& h, short& l) {
    unsigned u = __float_as_uint(f);
    unsigned r = u + 0x7FFFu + ((u >> 16) & 1u);
    h = (short)(r >> 16);
    float hf = __uint_as_float(r & 0xFFFF0000u);
    float lf = f - hf;
    unsigned u2 = __float_as_uint(lf);
    unsigned r2 = u2 + 0x7FFFu + ((u2 >> 16) & 1u);
    l = (short)(r2 >> 16);
}

__device__ inline void split4(const float4 v, uint2& hi, uint2& lo) {
    short h0, h1, h2, h3, l0, l1, l2, l3;
    split_bf16(v.x, h0, l0); split_bf16(v.y, h1, l1);
    split_bf16(v.z, h2, l2); split_bf16(v.w, h3, l3);
    hi.x = (unsigned short)h0 | ((unsigned)(unsigned short)h1 << 16);
    hi.y = (unsigned short)h2 | ((unsigned)(unsigned short)h3 << 16);
    lo.x = (unsigned short)l0 | ((unsigned)(unsigned short)l1 << 16);
    lo.y = (unsigned short)l2 | ((unsigned)(unsigned short)l3 << 16);
}

// ---------------- 1) GroupNorm stats + zero (qsum+sraw+ksum contiguous) ----------------
__global__ __launch_bounds__(256) void gn_zero_kernel(
    const float* __restrict__ x, const float* __restrict__ gamma,
    const float* __restrict__ beta, float* __restrict__ scale, float* __restrict__ shift,
    float* __restrict__ zbase) {
    if (blockIdx.x >= 256) {
        ((float4*)zbase)[(blockIdx.x - 256) * 256 + threadIdx.x] =
            make_float4(0.f, 0.f, 0.f, 0.f);
        return;
    }
    int b = blockIdx.x >> 5, g = blockIdx.x & 31;
    const float4* p = (const float4*)(x + ((size_t)b * CH + 2 * g) * NPIX);
    float s = 0.f, ss = 0.f;
#pragma unroll
    for (int i = 0; i < 8; ++i) {
        float4 v = p[threadIdx.x + i * 256];
        s += v.x + v.y + v.z + v.w;
        ss += v.x * v.x + v.y * v.y + v.z * v.z + v.w * v.w;
    }
    s = wave_sum(s);
    ss = wave_sum(ss);
    __shared__ float rs[4], rss[4];
    int lane = threadIdx.x & 63, wv = threadIdx.x >> 6;
    if (lane == 0) { rs[wv] = s; rss[wv] = ss; }
    __syncthreads();
    if (threadIdx.x == 0) {
        s = rs[0] + rs[1] + rs[2] + rs[3];
        ss = rss[0] + rss[1] + rss[2] + rss[3];
        float mu = s * (1.f / 8192.f);
        float var = ss * (1.f / 8192.f) - mu * mu;
        float rstd = rsqrtf(var + 1e-6f);
#pragma unroll
        for (int cc = 0; cc < 2; ++cc) {
            int c = 2 * g + cc;
            float sc = rstd * gamma[c];
            scale[b * CH + c] = sc;
            shift[b * CH + c] = beta[c] - mu * sc;
        }
    }
}

// ---------------- 2) GEMM1-Q: expq = exp(Wq@xn + bq)  (R7/R8-proven, NO fused rowsum) ----
// R9 lesson: in-epilogue shfl-chain rowsum made this latency-bound (70 us, all pipes idle).
__global__ __launch_bounds__(256) void gemm1_q_kernel(
    const float* __restrict__ x, const float* __restrict__ scale_all,
    const float* __restrict__ shift_all,
    const float* __restrict__ Wq, const float* __restrict__ bq,
    float* __restrict__ qkv) {
    __shared__ __align__(16) char lds[65536];
    short* As = (short*)lds;
    short* Bs = (short*)(lds + 32768);
    float* Bf = (float*)lds;

    int t = threadIdx.x;
    int b = blockIdx.z;
    int row0 = blockIdx.y * 128, pix0 = blockIdx.x * 128;

    float4 w4[8];
#pragma unroll
    for (int i = 0; i < 8; ++i) {
        int idx = t + i * 256;
        int r = idx >> 4, c4 = idx & 15;
        w4[i] = *(const float4*)(Wq + (size_t)(row0 + r) * 64 + c4 * 4);
    }
    const float* scale = scale_all + b * CH;
    const float* shift = shift_all + b * CH;
#pragma unroll
    for (int i = 0; i < 8; ++i) {
        int idx = t + i * 256;
        int c = idx >> 5, p4 = (idx & 31) * 4;
        float4 v = *(const float4*)(x + ((size_t)b * CH + c) * NPIX + pix0 + p4);
        float sc = scale[c], sh = shift[c];
        v.x = fmaf(v.x, sc, sh); v.y = fmaf(v.y, sc, sh);
        v.z = fmaf(v.z, sc, sh); v.w = fmaf(v.w, sc, sh);
        *(float4*)&Bf[c * 132 + p4] = v;
    }
    __syncthreads();
    int mypx = t & 127, chalf = t >> 7;
    float xv[32];
#pragma unroll
    for (int e = 0; e < 32; ++e) xv[e] = Bf[(chalf * 32 + e) * 132 + mypx];
    __syncthreads();
#pragma unroll
    for (int i = 0; i < 8; ++i) {
        int idx = t + i * 256;
        int r = idx >> 4, c4 = (idx & 15) * 4;
        uint2 hi, lo;
        split4(w4[i], hi, lo);
        int chh = ((c4 >> 3) ^ (r & 7));
        int chl = ((8 + (c4 >> 3)) ^ (r & 7));
        *(uint2*)&As[r * 128 + chh * 8 + (c4 & 7)] = hi;
        *(uint2*)&As[r * 128 + chl * 8 + (c4 & 7)] = lo;
    }
    {
        short h[32], l[32];
#pragma unroll
        for (int e = 0; e < 32; ++e) split_bf16(xv[e], h[e], l[e]);
#pragma unroll
        for (int w = 0; w < 4; ++w) {
            short8v hv, lv;
#pragma unroll
            for (int e = 0; e < 8; ++e) { hv[e] = h[w * 8 + e]; lv[e] = l[w * 8 + e]; }
            int chh = ((chalf * 4 + w) ^ (mypx & 7));
            int chl = ((8 + chalf * 4 + w) ^ (mypx & 7));
            *(short8v*)&Bs[mypx * 128 + chh * 8] = hv;
            *(short8v*)&Bs[mypx * 128 + chl * 8] = lv;
        }
    }
    __syncthreads();

    int lane = t & 63, wid = t >> 6;
    int wm = wid >> 1, wn = wid & 1;
    int l31 = lane & 31, l7 = lane & 7, kg = lane >> 5;
    int arow = wm * 64 + l31;
    int brow = wn * 64 + l31;
    f32x16 acc[2][2];
#pragma unroll
    for (int mt = 0; mt < 2; ++mt)
#pragma unroll
        for (int nt = 0; nt < 2; ++nt)
#pragma unroll
            for (int e = 0; e < 16; ++e) acc[mt][nt][e] = 0.f;
    const int ACH[12] = {0, 2, 4, 6, 8, 10, 12, 14, 0, 2, 4, 6};
    const int BCH[12] = {0, 2, 4, 6, 0, 2, 4, 6, 8, 10, 12, 14};
#pragma unroll
    for (int ks = 0; ks < 12; ++ks) {
        int ach = ACH[ks] + kg, bch = BCH[ks] + kg;
        short8v a0 = *(const short8v*)&As[arow * 128 + ((ach ^ l7) << 3)];
        short8v a1 = *(const short8v*)&As[(arow + 32) * 128 + ((ach ^ l7) << 3)];
        short8v b0 = *(const short8v*)&Bs[brow * 128 + ((bch ^ l7) << 3)];
        short8v b1 = *(const short8v*)&Bs[(brow + 32) * 128 + ((bch ^ l7) << 3)];
        acc[0][0] = __builtin_amdgcn_mfma_f32_32x32x16_bf16(a0, b0, acc[0][0], 0, 0, 0);
        acc[0][1] = __builtin_amdgcn_mfma_f32_32x32x16_bf16(a0, b1, acc[0][1], 0, 0, 0);
        acc[1][0] = __builtin_amdgcn_mfma_f32_32x32x16_bf16(a1, b0, acc[1][0], 0, 0, 0);
        acc[1][1] = __builtin_amdgcn_mfma_f32_32x32x16_bf16(a1, b1, acc[1][1], 0, 0, 0);
    }
#pragma unroll
    for (int mt = 0; mt < 2; ++mt) {
#pragma unroll
        for (int j = 0; j < 16; ++j) {
            int rl = wm * 64 + mt * 32 + (j & 3) + 8 * (j >> 2) + 4 * kg;
            float bi = bq[row0 + rl];
#pragma unroll
            for (int nt = 0; nt < 2; ++nt) {
                float val = __expf(acc[mt][nt][j] + bi);
                qkv[((size_t)b * QROWS + row0 + rl) * NPIX + pix0 + wn * 64 + nt * 32 + l31] = val;
            }
        }
    }
}

// ---------------- 3) fused KV, 512 threads (8 waves = 2 waves/SIMD) ----
// grid (32 pxtiles, 4 kvtiles, 8 b). Projection swapped: A=xn(px), B=W(krow).
// expk/v -> LDS chunk-XOR bufs; contraction: one 32x32 s-tile per wave over K=128 px;
// atomicAdd -> sraw. k,v never hit HBM.
__global__ __launch_bounds__(512) void gemm_kv_fused_kernel(
    const float* __restrict__ x, const float* __restrict__ scale_all,
    const float* __restrict__ shift_all,
    const float* __restrict__ Wk, const float* __restrict__ bk,
    const float* __restrict__ Wv, const float* __restrict__ bv,
    float* __restrict__ sraw, float* __restrict__ ksum) {
    __shared__ __align__(16) char lds[131072];
    short* As = (short*)lds;
    short* Bs = (short*)(lds + 32768);
    short* Eh = (short*)(lds + 65536);
    short* El = (short*)(lds + 98304);
    short* Vh = (short*)lds;            // overlays As after v-projection
    short* Vl = (short*)(lds + 32768);  // overlays Bs
    float* Bf = (float*)lds;

    int t = threadIdx.x;
    int b = blockIdx.z;
    int r = blockIdx.y;
    int pix0 = blockIdx.x * 128;

    float4 w4[4];
#pragma unroll
    for (int i = 0; i < 4; ++i) {
        int idx = t + i * 512;
        int rr = idx >> 4, c4 = idx & 15;
        w4[i] = *(const float4*)(Wk + (size_t)(r * 128 + rr) * 64 + c4 * 4);
    }
    const float* scale = scale_all + b * CH;
    const float* shift = shift_all + b * CH;
#pragma unroll
    for (int i = 0; i < 4; ++i) {
        int idx = t + i * 512;
        int c = idx >> 5, p4 = (idx & 31) * 4;
        float4 v = *(const float4*)(x + ((size_t)b * CH + c) * NPIX + pix0 + p4);
        float sc = scale[c], sh = shift[c];
        v.x = fmaf(v.x, sc, sh); v.y = fmaf(v.y, sc, sh);
        v.z = fmaf(v.z, sc, sh); v.w = fmaf(v.w, sc, sh);
        *(float4*)&Bf[c * 132 + p4] = v;
    }
    __syncthreads();
    int mypx = t & 127, cq = t >> 7;
    float xv[16];
#pragma unroll
    for (int e = 0; e < 16; ++e) xv[e] = Bf[(cq * 16 + e) * 132 + mypx];
    __syncthreads();
#pragma unroll
    for (int i = 0; i < 4; ++i) {
        int idx = t + i * 512;
        int rr = idx >> 4, c4 = (idx & 15) * 4;
        uint2 hi, lo;
        split4(w4[i], hi, lo);
        int chh = ((c4 >> 3) ^ (rr & 7));
        int chl = ((8 + (c4 >> 3)) ^ (rr & 7));
        *(uint2*)&As[rr * 128 + chh * 8 + (c4 & 7)] = hi;
        *(uint2*)&As[rr * 128 + chl * 8 + (c4 & 7)] = lo;
    }
    {
        short h[16], l[16];
#pragma unroll
        for (int e = 0; e < 16; ++e) split_bf16(xv[e], h[e], l[e]);
#pragma unroll
        for (int w = 0; w < 2; ++w) {
            short8v hv, lv;
#pragma unroll
            for (int e = 0; e < 8; ++e) { hv[e] = h[w * 8 + e]; lv[e] = l[w * 8 + e]; }
            int chh = ((cq * 2 + w) ^ (mypx & 7));
            int chl = ((8 + cq * 2 + w) ^ (mypx & 7));
            *(short8v*)&Bs[mypx * 128 + chh * 8] = hv;
            *(short8v*)&Bs[mypx * 128 + chl * 8] = lv;
        }
    }
    float4 w4v[4];
#pragma unroll
    for (int i = 0; i < 4; ++i) {
        int idx = t + i * 512;
        int rr = idx >> 4, c4 = idx & 15;
        w4v[i] = *(const float4*)(Wv + (size_t)(r * 128 + rr) * 64 + c4 * 4);
    }
    __syncthreads();

    int lane = t & 63, wid = t >> 6;
    int wm = wid >> 2, wn = wid & 3;
    int l31 = lane & 31, l7 = lane & 7, kg = lane >> 5;
    int axrow = wm * 64 + l31;
    int bwrow = wn * 32 + l31;
    const int XCH[12] = {0, 2, 4, 6, 8, 10, 12, 14, 0, 2, 4, 6};
    const int WCH[12] = {0, 2, 4, 6, 0, 2, 4, 6, 8, 10, 12, 14};

    f32x16 acc[2];
#pragma unroll
    for (int mt = 0; mt < 2; ++mt)
#pragma unroll
        for (int e = 0; e < 16; ++e) acc[mt][e] = 0.f;
#pragma unroll
    for (int ks = 0; ks < 12; ++ks) {
        int xch = XCH[ks] + kg, wch = WCH[ks] + kg;
        short8v a0 = *(const short8v*)&Bs[axrow * 128 + ((xch ^ l7) << 3)];
        short8v a1 = *(const short8v*)&Bs[(axrow + 32) * 128 + ((xch ^ l7) << 3)];
        short8v b0 = *(const short8v*)&As[bwrow * 128 + ((wch ^ l7) << 3)];
        acc[0] = __builtin_amdgcn_mfma_f32_32x32x16_bf16(a0, b0, acc[0], 0, 0, 0);
        acc[1] = __builtin_amdgcn_mfma_f32_32x32x16_bf16(a1, b0, acc[1], 0, 0, 0);
    }
    {
        int krow = wn * 32 + l31;
        float bi = bk[r * 128 + krow];
        float part = 0.f;
#pragma unroll
        for (int mt = 0; mt < 2; ++mt) {
#pragma unroll
            for (int g = 0; g < 4; ++g) {
                float4 ev;
                ev.x = __expf(acc[mt][g * 4 + 0] + bi);
                ev.y = __expf(acc[mt][g * 4 + 1] + bi);
                ev.z = __expf(acc[mt][g * 4 + 2] + bi);
                ev.w = __expf(acc[mt][g * 4 + 3] + bi);
                part += ev.x + ev.y + ev.z + ev.w;
                uint2 hi, lo;
                split4(ev, hi, lo);
                int ch = wm * 8 + mt * 4 + g;
                int off = krow * 128 + ((ch ^ (krow & 7)) << 3) + 4 * kg;
                *(uint2*)&Eh[off] = hi;
                *(uint2*)&El[off] = lo;
            }
        }
        part += __shfl_xor(part, 32);
        if (kg == 0) atomicAdd(&ksum[b * 512 + r * 128 + krow], part);
    }
    __syncthreads();
#pragma unroll
    for (int i = 0; i < 4; ++i) {
        int idx = t + i * 512;
        int rr = idx >> 4, c4 = (idx & 15) * 4;
        uint2 hi, lo;
        split4(w4v[i], hi, lo);
        int chh = ((c4 >> 3) ^ (rr & 7));
        int chl = ((8 + (c4 >> 3)) ^ (rr & 7));
        *(uint2*)&As[rr * 128 + chh * 8 + (c4 & 7)] = hi;
        *(uint2*)&As[rr * 128 + chl * 8 + (c4 & 7)] = lo;
    }
    __syncthreads();
#pragma unroll
    for (int mt = 0; mt < 2; ++mt)
#pragma unroll
        for (int e = 0; e < 16; ++e) acc[mt][e] = 0.f;
#pragma unroll
    for (int ks = 0; ks < 12; ++ks) {
        int xch = XCH[ks] + kg, wch = WCH[ks] + kg;
        short8v a0 = *(const short8v*)&Bs[axrow * 128 + ((xch ^ l7) << 3)];
        short8v a1 = *(const short8v*)&Bs[(axrow + 32) * 128 + ((xch ^ l7) << 3)];
        short8v b0 = *(const short8v*)&As[bwrow * 128 + ((wch ^ l7) << 3)];
        acc[0] = __builtin_amdgcn_mfma_f32_32x32x16_bf16(a0, b0, acc[0], 0, 0, 0);
        acc[1] = __builtin_amdgcn_mfma_f32_32x32x16_bf16(a1, b0, acc[1], 0, 0, 0);
    }
    __syncthreads();
    {
        int vrow = wn * 32 + l31;
        float bi = bv[r * 128 + vrow];
#pragma unroll
        for (int mt = 0; mt < 2; ++mt) {
#pragma unroll
            for (int g = 0; g < 4; ++g) {
                float4 vv;
                vv.x = acc[mt][g * 4 + 0] + bi;
                vv.y = acc[mt][g * 4 + 1] + bi;
                vv.z = acc[mt][g * 4 + 2] + bi;
                vv.w = acc[mt][g * 4 + 3] + bi;
                uint2 hi, lo;
                split4(vv, hi, lo);
                int ch = wm * 8 + mt * 4 + g;
                int off = vrow * 128 + ((ch ^ (vrow & 7)) << 3) + 4 * kg;
                *(uint2*)&Vh[off] = hi;
                *(uint2*)&Vl[off] = lo;
            }
        }
    }
    __syncthreads();
    int hh = wid >> 2, pc = wid & 3;
    int pp = pc >> 1, cc = pc & 1;
    int ar = (hh * 64 + pp * 32 + l31) * 128;
    int br = (hh * 64 + cc * 32 + l31) * 128;
    f32x16 cacc;
#pragma unroll
    for (int e = 0; e < 16; ++e) cacc[e] = 0.f;
#pragma unroll
    for (int s = 0; s < 8; ++s) {
        int ch = (((2 * s + kg) ^ l7) << 3);
        short8v a = *(const short8v*)&Eh[ar + ch];
        short8v bb = *(const short8v*)&Vh[br + ch];
        cacc = __builtin_amdgcn_mfma_f32_32x32x16_bf16(a, bb, cacc, 0, 0, 0);
    }
#pragma unroll
    for (int s = 0; s < 8; ++s) {
        int ch = (((2 * s + kg) ^ l7) << 3);
        short8v a = *(const short8v*)&El[ar + ch];
        short8v bb = *(const short8v*)&Vh[br + ch];
        cacc = __builtin_amdgcn_mfma_f32_32x32x16_bf16(a, bb, cacc, 0, 0, 0);
    }
#pragma unroll
    for (int s = 0; s < 8; ++s) {
        int ch = (((2 * s + kg) ^ l7) << 3);
        short8v a = *(const short8v*)&Eh[ar + ch];
        short8v bb = *(const short8v*)&Vl[br + ch];
        cacc = __builtin_amdgcn_mfma_f32_32x32x16_bf16(a, bb, cacc, 0, 0, 0);
    }
    int h = r * 2 + hh;
    float* sr = sraw + (((size_t)b * 8 + h) * 64) * 64;
#pragma unroll
    for (int j = 0; j < 16; ++j) {
        int p = pp * 32 + (j & 3) + 8 * (j >> 2) + 4 * kg;
        int c = cc * 32 + l31;
        atomicAdd(&sr[p * 64 + c], cacc[j]);
    }
}

// ---------------- 4) row sums of expq (separate streaming kernel — R9 fusion regressed) ----
__global__ __launch_bounds__(256) void rowsum_q_kernel(
    const float* __restrict__ qkv, float* __restrict__ qsum) {
    int b = blockIdx.x >> 9, row = blockIdx.x & 511;
    const float4* p = (const float4*)(qkv + ((size_t)b * QROWS + row) * NPIX);
    float s = 0.f;
#pragma unroll
    for (int i = 0; i < 4; ++i) {
        float4 v = p[threadIdx.x + i * 256];
        s += v.x + v.y + v.z + v.w;
    }
    s = wave_sum(s);
    __shared__ float rs[4];
    int lane = threadIdx.x & 63, wv = threadIdx.x >> 6;
    if (lane == 0) rs[wv] = s;
    __syncthreads();
    if (threadIdx.x == 0)
        qsum[b * 512 + row] = rs[0] + rs[1] + rs[2] + rs[3];
}

// ---------------- 5) T[b,o,hp] = (Wo[o,h*64:] . sraw[b,h,p,:]) / (8*ksum*qsum) --------
__global__ __launch_bounds__(256) void t_kernel(
    const float* __restrict__ sraw, const float* __restrict__ qsum_all,
    const float* __restrict__ ksum_all, const float* __restrict__ Wo, float* __restrict__ T) {
    int idx = blockIdx.x * 256 + threadIdx.x;
    int hp = idx & 511, o = (idx >> 9) & 63, b = idx >> 15;
    int h = hp >> 6, pp = hp & 63;
    const float* srow = sraw + (((size_t)b * 8 + h) * 64 + pp) * 64;
    const float* wrow = Wo + (size_t)o * 512 + h * 64;
    float acc = 0.f;
#pragma unroll
    for (int c = 0; c < 64; ++c) acc += wrow[c] * srow[c];
    float ks = ksum_all[b * 512 + hp];
    float qs = qsum_all[b * 512 + hp];
    T[idx] = acc / (8.f * ks * qs);
}

// ---------------- 6) GEMM2 via MFMA: out[b,o,px] = bo[o] + sum_hp T[o,hp]*expq[hp,px] --
__global__ __launch_bounds__(256) void gemm2_mfma_kernel(
    const float* __restrict__ qkv, const float* __restrict__ T_all,
    const float* __restrict__ bo, float* __restrict__ out) {
    __shared__ __align__(16) short lds[16384];
    short* As = lds;
    short* Bs = lds + 8192;
    int pix0 = blockIdx.x * 64, b = blockIdx.y;
    const float* Tb = T_all + (size_t)b * 64 * 512;
    const float* qb = qkv + (size_t)b * QROWS * NPIX;
    int t = threadIdx.x;
    int lane = t & 63, wid = t >> 6;
    int wm = wid & 1, wn = wid >> 1;
    int l31 = lane & 31, l7 = lane & 7, kg = lane >> 5;
    int arow = (wm * 32 + l31) * 128;
    int brow = (wn * 32 + l31) * 128;
    int px0 = t & 63, hpq = (t >> 6) * 16;
    f32x16 acc;
#pragma unroll
    for (int e = 0; e < 16; ++e) acc[e] = 0.f;
    for (int it = 0; it < 8; ++it) {
        __syncthreads();
#pragma unroll
        for (int i = 0; i < 4; ++i) {
            int e4 = t + i * 256;
            int o = e4 >> 4, p4 = (e4 & 15) * 4;
            int chx = (((p4 >> 3) ^ (o & 7)) << 3) + (p4 & 7);
            float4 tv = *(const float4*)(Tb + (size_t)o * 512 + it * 64 + p4);
            uint2 hi, lo;
            split4(tv, hi, lo);
            *(uint2*)&As[o * 128 + chx] = hi;
            *(uint2*)&As[o * 128 + 64 + chx] = lo;
        }
        float colv[16];
#pragma unroll
        for (int e = 0; e < 16; ++e)
            colv[e] = qb[(size_t)(it * 64 + hpq + e) * NPIX + pix0 + px0];
#pragma unroll
        for (int qd = 0; qd < 4; ++qd) {
            int hpl = hpq + qd * 4;
            float4 v4 = make_float4(colv[qd * 4], colv[qd * 4 + 1],
                                    colv[qd * 4 + 2], colv[qd * 4 + 3]);
            uint2 hi, lo;
            split4(v4, hi, lo);
            int chx = (((hpl >> 3) ^ (px0 & 7)) << 3) + (hpl & 7);
            *(uint2*)&Bs[px0 * 128 + chx] = hi;
            *(uint2*)&Bs[px0 * 128 + 64 + chx] = lo;
        }
        __syncthreads();
        short8v ah[4], al[4], bh[4], bl[4];
#pragma unroll
        for (int ks = 0; ks < 4; ++ks) {
            int ch = ((ks * 2 + kg) ^ l7) << 3;
            ah[ks] = *(const short8v*)&As[arow + ch];
            al[ks] = *(const short8v*)&As[arow + 64 + ch];
            bh[ks] = *(const short8v*)&Bs[brow + ch];
            bl[ks] = *(const short8v*)&Bs[brow + 64 + ch];
        }
#pragma unroll
        for (int ks = 0; ks < 4; ++ks) {
            acc = __builtin_amdgcn_mfma_f32_32x32x16_bf16(ah[ks], bh[ks], acc, 0, 0, 0);
            acc = __builtin_amdgcn_mfma_f32_32x32x16_bf16(al[ks], bh[ks], acc, 0, 0, 0);
            acc = __builtin_amdgcn_mfma_f32_32x32x16_bf16(ah[ks], bl[ks], acc, 0, 0, 0);
        }
    }
#pragma unroll
    for (int j = 0; j < 16; ++j) {
        int o = wm * 32 + (j & 3) + 8 * (j >> 2) + 4 * kg;
        out[((size_t)b * 64 + o) * NPIX + pix0 + wn * 32 + l31] = acc[j] + bo[o];
    }
}

// ---------------- workspace layout (floats) ----------------
#define OFF_SCALE 0                     // [8][64]          = 512
#define OFF_SHIFT 512                   // [8][64]          = 512
#define OFF_QSUM  1024                  // [8][512]         = 4096
#define OFF_SRAW  5120                  // [8][8][64][64]   = 262144
#define OFF_KSUM  267264                // [8][512]         = 4096
#define OFF_T     271360                // [8][64][512]     = 262144
#define OFF_QKV   533504                // [8][512][4096]   = 16777216 (expq only)
#define WS_FLOATS (533504 + 16777216)
// zero range [OFF_QSUM, OFF_KSUM+4096) = 270336 floats = 67584 float4 = 264 blocks * 256

extern "C" void kernel_launch(void* const* d_in, const int* in_sizes, int n_in,
                              void* d_out, int out_size, void* d_ws, size_t ws_size,
                              hipStream_t stream) {
    const float* x  = (const float*)d_in[0];
    const float* gg = (const float*)d_in[1];
    const float* gb = (const float*)d_in[2];
    const float* Wq = (const float*)d_in[3];
    const float* bq = (const float*)d_in[4];
    const float* Wk = (const float*)d_in[5];
    const float* bk = (const float*)d_in[6];
    const float* Wv = (const float*)d_in[7];
    const float* bv = (const float*)d_in[8];
    const float* Wo = (const float*)d_in[9];
    const float* bo = (const float*)d_in[10];
    float* out = (float*)d_out;
    float* ws = (float*)d_ws;
    if (ws_size < (size_t)WS_FLOATS * sizeof(float)) return;

    float* scale = ws + OFF_SCALE;
    float* shift = ws + OFF_SHIFT;
    float* qsum  = ws + OFF_QSUM;
    float* sraw  = ws + OFF_SRAW;
    float* ksum  = ws + OFF_KSUM;
    float* T     = ws + OFF_T;
    float* qkv   = ws + OFF_QKV;

    gn_zero_kernel<<<520, 256, 0, stream>>>(x, gg, gb, scale, shift, qsum);
    gemm1_q_kernel<<<dim3(32, 4, 8), 256, 0, stream>>>(x, scale, shift, Wq, bq, qkv);
    gemm_kv_fused_kernel<<<dim3(32, 4, 8), 512, 0, stream>>>(x, scale, shift, Wk, bk, Wv, bv,
                                                             sraw, ksum);
    rowsum_q_kernel<<<4096, 256, 0, stream>>>(qkv, qsum);
    t_kernel<<<1024, 256, 0, stream>>>(sraw, qsum, ksum, Wo, T);
    gemm2_mfma_kernel<<<dim3(64, 8), 256, 0, stream>>>(qkv, T, bo, out);
}